// Round 6
// baseline (393.564 us; speedup 1.0000x reference)
//
#include <hip/hip_runtime.h>
#include <hip/hip_bf16.h>
#include <cmath>

#define F_IN 128
#define HDIM 64
#define NPB 128          // nodes per bucket (node >> 7)
#define CAP 2560         // col capacity per bucket (mean 2046, +11 sigma)

typedef __attribute__((ext_vector_type(8))) short bf16x8;
typedef __attribute__((ext_vector_type(4))) float f32x4;
typedef __attribute__((ext_vector_type(2))) float f32x2;

__device__ __forceinline__ float bf2f(unsigned short u) {
    union { unsigned int i; float f; } v; v.i = ((unsigned int)u) << 16; return v.f;
}
__device__ __forceinline__ unsigned short f2bf(float f) {
    __hip_bfloat16 h = __float2bfloat16(f);
    union { __hip_bfloat16 h; unsigned short u; } c; c.h = h; return c.u;
}
__device__ __forceinline__ unsigned char f2fp8(float f) {
    int p = __builtin_amdgcn_cvt_pk_fp8_f32(f, f, 0, false);
    return (unsigned char)(p & 0xff);
}
__device__ __forceinline__ void fp8x8_acc(uint2 v, float* a) {
    f32x2 f;
    f = __builtin_amdgcn_cvt_pk_f32_fp8(v.x, false); a[0] += f.x; a[1] += f.y;
    f = __builtin_amdgcn_cvt_pk_f32_fp8(v.x, true);  a[2] += f.x; a[3] += f.y;
    f = __builtin_amdgcn_cvt_pk_f32_fp8(v.y, false); a[4] += f.x; a[5] += f.y;
    f = __builtin_amdgcn_cvt_pk_f32_fp8(v.y, true);  a[6] += f.x; a[7] += f.y;
}
__device__ __forceinline__ void fp8x8_acc_m(uint2 v, float m, float* a) {
    f32x2 f;
    f = __builtin_amdgcn_cvt_pk_f32_fp8(v.x, false); a[0] = fmaf(f.x, m, a[0]); a[1] = fmaf(f.y, m, a[1]);
    f = __builtin_amdgcn_cvt_pk_f32_fp8(v.x, true);  a[2] = fmaf(f.x, m, a[2]); a[3] = fmaf(f.y, m, a[3]);
    f = __builtin_amdgcn_cvt_pk_f32_fp8(v.y, false); a[4] = fmaf(f.x, m, a[4]); a[5] = fmaf(f.y, m, a[5]);
    f = __builtin_amdgcn_cvt_pk_f32_fp8(v.y, true);  a[6] = fmaf(f.x, m, a[6]); a[7] = fmaf(f.y, m, a[7]);
}

// Gather: 8 lanes/slot, uint2 rows, 8-edge independent rounds; tail is ONE
// clamped+masked round (1 memory latency) instead of a serial dependent chain.
__device__ __forceinline__ void gather_rows(const int* __restrict__ col,
                                            const uint2* __restrict__ xws,
                                            int L, int s, int end, float* a) {
    int e = s;
    for (; e + 8 <= end; e += 8) {
        uint2 v0 = xws[(size_t)col[e + 0] * 8 + L];
        uint2 v1 = xws[(size_t)col[e + 1] * 8 + L];
        uint2 v2 = xws[(size_t)col[e + 2] * 8 + L];
        uint2 v3 = xws[(size_t)col[e + 3] * 8 + L];
        uint2 v4 = xws[(size_t)col[e + 4] * 8 + L];
        uint2 v5 = xws[(size_t)col[e + 5] * 8 + L];
        uint2 v6 = xws[(size_t)col[e + 6] * 8 + L];
        uint2 v7 = xws[(size_t)col[e + 7] * 8 + L];
        fp8x8_acc(v0, a); fp8x8_acc(v1, a); fp8x8_acc(v2, a); fp8x8_acc(v3, a);
        fp8x8_acc(v4, a); fp8x8_acc(v5, a); fp8x8_acc(v6, a); fp8x8_acc(v7, a);
    }
    if (e < end) {
        int last = end - 1;
        uint2 v0 = xws[(size_t)col[e]               * 8 + L];
        uint2 v1 = xws[(size_t)col[min(e + 1, last)] * 8 + L];
        uint2 v2 = xws[(size_t)col[min(e + 2, last)] * 8 + L];
        uint2 v3 = xws[(size_t)col[min(e + 3, last)] * 8 + L];
        uint2 v4 = xws[(size_t)col[min(e + 4, last)] * 8 + L];
        uint2 v5 = xws[(size_t)col[min(e + 5, last)] * 8 + L];
        uint2 v6 = xws[(size_t)col[min(e + 6, last)] * 8 + L];
        uint2 v7 = xws[(size_t)col[min(e + 7, last)] * 8 + L];
        fp8x8_acc(v0, a);
        fp8x8_acc_m(v1, (e + 1 < end) ? 1.0f : 0.0f, a);
        fp8x8_acc_m(v2, (e + 2 < end) ? 1.0f : 0.0f, a);
        fp8x8_acc_m(v3, (e + 3 < end) ? 1.0f : 0.0f, a);
        fp8x8_acc_m(v4, (e + 4 < end) ? 1.0f : 0.0f, a);
        fp8x8_acc_m(v5, (e + 5 < end) ? 1.0f : 0.0f, a);
        fp8x8_acc_m(v6, (e + 6 < end) ? 1.0f : 0.0f, a);
        fp8x8_acc_m(v7, (e + 7 < end) ? 1.0f : 0.0f, a);
    }
}

// ========== K1: init — W transposes + graph bounds + zero deg ==========

__launch_bounds__(256)
__global__ void k_init(const float* __restrict__ W1, const float* __restrict__ W2,
                       unsigned short* __restrict__ w1t, unsigned short* __restrict__ w2t,
                       const int* __restrict__ batch, int* __restrict__ gstart,
                       int n, int G, int* __restrict__ deg) {
    int t = blockIdx.x * 256 + threadIdx.x;
    if (t < F_IN * 64) {                       // w1t[c][k] = W1[k][c]
        int c = t & 63, k = t >> 6;
        w1t[c * F_IN + k] = f2bf(W1[t]);
        return;
    }
    t -= F_IN * 64;
    if (t < HDIM * 64) {                       // w2t[c][k] = W2[k][c]
        int c = t & 63, k = t >> 6;
        w2t[c * HDIM + k] = f2bf(W2[t]);
        return;
    }
    t -= HDIM * 64;
    if (t <= G) {                              // gstart: first node of graph t
        int g = t;
        int lo = 0, hi = n;
        while (lo < hi) {
            int mid = (lo + hi) >> 1;
            if (batch[mid] < g) lo = mid + 1; else hi = mid;
        }
        gstart[g] = lo;
        return;
    }
    t -= G + 1;
    if (t < n) deg[t] = 0;
}

// ========== K2: degree count — fire-and-forget scattered atomics ==========

__launch_bounds__(256)
__global__ void k_deg(const int* __restrict__ dst, int* __restrict__ deg, int E) {
    int e = (blockIdx.x * 256 + threadIdx.x) * 4;
    if (e + 4 <= E) {
        int4 d = *(const int4*)(dst + e);
        atomicAdd(&deg[d.x], 1);
        atomicAdd(&deg[d.y], 1);
        atomicAdd(&deg[d.z], 1);
        atomicAdd(&deg[d.w], 1);
    } else {
        for (; e < E; ++e) atomicAdd(&deg[dst[e]], 1);
    }
}

// ========== K3: per-bucket headers from deg — scan, dinv, curpos, sorted slots ==========

__launch_bounds__(128)
__global__ void p2_hdr(const int* __restrict__ deg, float* __restrict__ dinv,
                       int* __restrict__ curpos, int4* __restrict__ slot_hdr, int n) {
    __shared__ int sc[128];
    __shared__ int h64[64];
    __shared__ int s64[64];
    int b = blockIdx.x, tid = threadIdx.x;
    int nlo = b << 7;
    int eb = b * CAP;
    int node = nlo + tid;
    int d0 = (node < n) ? deg[node] : 0;
    sc[tid] = d0;
    if (tid < 64) h64[tid] = 0;
    __syncthreads();
    for (int off = 1; off < 128; off <<= 1) {
        int a = (tid >= off) ? sc[tid - off] : 0;
        __syncthreads();
        sc[tid] += a;
        __syncthreads();
    }
    int excl = sc[tid] - d0;
    float dv = rsqrtf((float)(d0 + 1));
    if (node < n) {
        dinv[node] = dv;
        curpos[node] = eb + excl;       // destructively consumed by k_place
    }
    atomicAdd(&h64[min(d0, 63)], 1);
    __syncthreads();
    if (tid == 0) { int run = 0; for (int i = 0; i < 64; ++i) { s64[i] = run; run += h64[i]; } }
    __syncthreads();
    if (tid < 64) h64[tid] = 0;
    __syncthreads();
    int bin = min(d0, 63);
    int pos = s64[bin] + atomicAdd(&h64[bin], 1);
    int4 hdr;
    hdr.x = (node < n) ? node : 0x7fffffff;
    hdr.y = eb + excl;
    hdr.z = d0;
    hdr.w = __float_as_int(dv);
    slot_hdr[nlo + pos] = hdr;
}

// ========== K4: place edges directly into CSR col (runs ~64B, line-coalesced) ==========

__launch_bounds__(256)
__global__ void k_place(const int* __restrict__ src, const int* __restrict__ dst,
                        int* __restrict__ curpos, int* __restrict__ col, int E) {
    int e = (blockIdx.x * 256 + threadIdx.x) * 4;
    if (e + 4 <= E) {
        int4 d = *(const int4*)(dst + e);
        int4 s = *(const int4*)(src + e);
        int p0 = atomicAdd(&curpos[d.x], 1);
        int p1 = atomicAdd(&curpos[d.y], 1);
        int p2 = atomicAdd(&curpos[d.z], 1);
        int p3 = atomicAdd(&curpos[d.w], 1);
        col[p0] = s.x; col[p1] = s.y; col[p2] = s.z; col[p3] = s.w;
    } else {
        for (; e < E; ++e) {
            int p = atomicAdd(&curpos[dst[e]], 1);
            col[p] = src[e];
        }
    }
}

// ========== K5: matmul1 (f32 X, K=128) -> fp8(xw * dinv) ==========

template <int K>
__launch_bounds__(256)
__global__ void matmul_mfma(const float* __restrict__ X, const unsigned short* __restrict__ Wt,
                            const float* __restrict__ dinv, unsigned char* __restrict__ out,
                            int n) {
    constexpr int KS  = K / 32;
    constexpr int LDX = K + 8;
    __shared__ unsigned short Xs[64 * LDX];
    __shared__ unsigned short Ws[64 * LDX];
    int tid = threadIdx.x;
    int rowbase = blockIdx.x * 64;
    for (int i = tid; i < 64 * (K / 8); i += 256) {
        int r = i / (K / 8), ch = i % (K / 8);
        *(bf16x8*)(Ws + r * LDX + ch * 8) = ((const bf16x8*)Wt)[i];
    }
    {
        const float4* X4 = (const float4*)X;
        for (int i = tid; i < 64 * (K / 4); i += 256) {
            int r = i / (K / 4), k4 = i % (K / 4);
            ushort4 u = { 0, 0, 0, 0 };
            int gr = rowbase + r;
            if (gr < n) {
                float4 v = X4[(size_t)gr * (K / 4) + k4];
                u.x = f2bf(v.x); u.y = f2bf(v.y); u.z = f2bf(v.z); u.w = f2bf(v.w);
            }
            *(ushort4*)(Xs + r * LDX + k4 * 4) = u;
        }
    }
    __syncthreads();
    int wave = tid >> 6, lane = tid & 63;
    int q = lane >> 4, nn = lane & 15;
    f32x4 acc[4] = {{0,0,0,0},{0,0,0,0},{0,0,0,0},{0,0,0,0}};
    int mrow = wave * 16 + nn;
#pragma unroll
    for (int s = 0; s < KS; ++s) {
        bf16x8 af = *(const bf16x8*)(Xs + mrow * LDX + s * 32 + q * 8);
#pragma unroll
        for (int c = 0; c < 4; ++c) {
            bf16x8 bf = *(const bf16x8*)(Ws + (c * 16 + nn) * LDX + s * 32 + q * 8);
            acc[c] = __builtin_amdgcn_mfma_f32_16x16x32_bf16(af, bf, acc[c], 0, 0, 0);
        }
    }
#pragma unroll
    for (int r = 0; r < 4; ++r) {
        int row = rowbase + wave * 16 + q * 4 + r;
        if (row >= n) continue;
        float dv = dinv[row];
#pragma unroll
        for (int c = 0; c < 4; ++c)
            out[(size_t)row * HDIM + c * 16 + nn] = f2fp8(acc[c][r] * dv);
    }
}

// ========== K6: gather1 + fused matmul2 (32-slot blocks) ==========

__launch_bounds__(256)
__global__ void gather1_mm2(const int4* __restrict__ slot_hdr, const int* __restrict__ col,
                            const uint2* __restrict__ xws, const float* __restrict__ bias,
                            const unsigned short* __restrict__ w2t,
                            unsigned char* __restrict__ out8, int nslots, int n) {
    __shared__ unsigned short Hs[32 * 72];   // h1 tile, bf16, row stride 72
    __shared__ unsigned short Ws[64 * 72];   // W2^T rows: Ws[c][k]
    __shared__ int   snode[32];
    __shared__ float sdinv[32];

    int tid = threadIdx.x;
    int ls = tid >> 3;          // local slot 0..31
    int L  = tid & 7;           // feature-octet lane
    int slot = blockIdx.x * 32 + ls;

    for (int i = tid; i < 64 * 8; i += 256) {
        int r = i >> 3, ch = i & 7;
        *(bf16x8*)(Ws + r * 72 + ch * 8) = ((const bf16x8*)w2t)[i];
    }

    // ---- gather phase ----
    int node = 0x7fffffff;
    float dv = 0.0f;
    float a[8] = {0, 0, 0, 0, 0, 0, 0, 0};
    if (slot < nslots) {
        int4 hdr = slot_hdr[slot];
        node = hdr.x;
        if (node < n) {
            dv = __int_as_float(hdr.w);
            fp8x8_acc(xws[(size_t)node * 8 + L], a);   // self-loop term
            gather_rows(col, xws, L, hdr.y, hdr.y + hdr.z, a);
        }
    }
    if (L == 0) { snode[ls] = node; sdinv[ls] = dv; }
    {
        int f0 = L * 8;
        bf16x8 o;
        if (node < n) {
#pragma unroll
            for (int j = 0; j < 8; ++j)
                o[j] = (short)f2bf(fmaxf(fmaf(a[j], dv, bias[f0 + j]), 0.0f));
        } else {
            short z[8] = {0,0,0,0,0,0,0,0};
            o = *(bf16x8*)z;
        }
        *(bf16x8*)(Hs + ls * 72 + L * 8) = o;
    }
    __syncthreads();

    // ---- matmul2 phase: D[32x64] = Hs @ W2, scaled by sdinv, emit fp8 ----
    int wave = tid >> 6, lane = tid & 63;
    int q = lane >> 4, nn = lane & 15;
    int mt  = wave & 1;          // M-tile (rows 0-15 / 16-31)
    int nt0 = (wave >> 1) * 2;   // N-tiles {nt0, nt0+1}
    f32x4 acc[2] = {{0,0,0,0},{0,0,0,0}};
#pragma unroll
    for (int s = 0; s < 2; ++s) {
        bf16x8 af = *(const bf16x8*)(Hs + (mt * 16 + nn) * 72 + s * 32 + q * 8);
#pragma unroll
        for (int t = 0; t < 2; ++t) {
            bf16x8 bf = *(const bf16x8*)(Ws + ((nt0 + t) * 16 + nn) * 72 + s * 32 + q * 8);
            acc[t] = __builtin_amdgcn_mfma_f32_16x16x32_bf16(af, bf, acc[t], 0, 0, 0);
        }
    }
#pragma unroll
    for (int r = 0; r < 4; ++r) {
        int lslot = mt * 16 + q * 4 + r;
        int nd = snode[lslot];
        if (nd >= n) continue;
        float dvr = sdinv[lslot];
#pragma unroll
        for (int t = 0; t < 2; ++t)
            out8[(size_t)nd * HDIM + (nt0 + t) * 16 + nn] = f2fp8(acc[t][r] * dvr);
    }
}

// ========== K7: gather2 — pure, barrier-free -> bf16 h2 ==========

__launch_bounds__(256)
__global__ void csr_gather8_fp8(const int4* __restrict__ slot_hdr, const int* __restrict__ col,
                                const uint2* __restrict__ xws, const float* __restrict__ bias,
                                bf16x8* __restrict__ outb, int nslots, int n) {
    int t = blockIdx.x * 256 + threadIdx.x;
    int slot = t >> 3;
    if (slot >= nslots) return;
    int L = t & 7;
    int4 hdr = slot_hdr[slot];
    int node = hdr.x;
    if (node >= n) return;
    float dv = __int_as_float(hdr.w);

    float a[8] = {0, 0, 0, 0, 0, 0, 0, 0};
    fp8x8_acc(xws[(size_t)node * 8 + L], a);
    gather_rows(col, xws, L, hdr.y, hdr.y + hdr.z, a);

    int f0 = L * 8;
    bf16x8 o;
#pragma unroll
    for (int j = 0; j < 8; ++j)
        o[j] = (short)f2bf(fmaxf(fmaf(a[j], dv, bias[f0 + j]), 0.0f));
    outb[(size_t)node * 8 + L] = o;
}

// ========== K8: mean-pool (bf16 rows) + head + sigmoid ==========

__launch_bounds__(256)
__global__ void pool_head(const unsigned short* __restrict__ h, const int* __restrict__ gstart,
                          const float* __restrict__ Wl, const float* __restrict__ bl,
                          float* __restrict__ out, int G) {
    int g = blockIdx.x;
    int s = gstart[g], e = gstart[g + 1];
    int f  = threadIdx.x & 63;
    int rg = threadIdx.x >> 6;
    float acc = 0.0f;
    for (int i = s + rg; i < e; i += 4)
        acc += bf2f(h[(size_t)i * HDIM + f]);
    __shared__ float red[4][HDIM];
    red[rg][f] = acc;
    __syncthreads();
    if (rg == 0) {
        float v = (red[0][f] + red[1][f]) + (red[2][f] + red[3][f]);
        float c = fmaxf((float)(e - s), 1.0f);
        v = v * Wl[f] * (1.0f / c);
#pragma unroll
        for (int off = 32; off; off >>= 1) v += __shfl_down(v, off, 64);
        if (f == 0) out[g] = 1.0f / (1.0f + expf(-(v + bl[0])));
    }
}

// ---------------- launch ----------------

extern "C" void kernel_launch(void* const* d_in, const int* in_sizes, int n_in,
                              void* d_out, int out_size, void* d_ws, size_t ws_size,
                              hipStream_t stream) {
    const float* x   = (const float*)d_in[0];
    const int* ei    = (const int*)d_in[1];
    const int* batch = (const int*)d_in[2];
    const float* W1  = (const float*)d_in[3];
    const float* b1  = (const float*)d_in[4];
    const float* W2  = (const float*)d_in[5];
    const float* b2  = (const float*)d_in[6];
    const float* Wl  = (const float*)d_in[7];
    const float* bl  = (const float*)d_in[8];
    float* out = (float*)d_out;

    const int n = in_sizes[0] / F_IN;   // 100000
    const int E = in_sizes[1] / 2;      // 1600000
    const int G = out_size;             // 512

    const int* srcp = ei;
    const int* dstp = ei + E;

    int nbuk = (n + NPB - 1) / NPB;     // 782
    int nslots = nbuk * NPB;            // 100096

    // workspace layout
    char* wsb = (char*)d_ws;
    auto alloc = [&](size_t bytes) { char* p = wsb; wsb += (bytes + 255) & ~(size_t)255; return p; };
    float* dinv       = (float*)alloc((size_t)n * 4);
    int4*  slot_hdr   = (int4*)alloc((size_t)nslots * 16);
    int*   deg        = (int*)alloc((size_t)n * 4);
    int*   curpos     = (int*)alloc((size_t)n * 4);
    int*   colx       = (int*)alloc((size_t)nbuk * CAP * 4);
    unsigned short* w1t  = (unsigned short*)alloc((size_t)F_IN * HDIM * 2);
    unsigned short* w2t  = (unsigned short*)alloc((size_t)HDIM * HDIM * 2);
    unsigned char*  xws8 = (unsigned char*)alloc((size_t)n * HDIM);       // fp8 payload L1
    unsigned char*  xws8b= (unsigned char*)alloc((size_t)n * HDIM);       // fp8 payload L2
    unsigned short* xh2  = (unsigned short*)alloc((size_t)n * HDIM * 2);  // layer-2 h (bf16)
    int*   gstart     = (int*)alloc(((size_t)G + 1) * 4);

    const int TB = 256;
    int gMM  = (n + 63) / 64;                         // 1563
    int gE4  = (E / 4 + TB - 1) / TB;                 // 1563
    int gG8  = (nslots * 8 + TB - 1) / TB;            // 3128
    int gS   = (nslots + 31) / 32;                    // 3128
    int initWork = F_IN * 64 + HDIM * 64 + (G + 1) + n;
    int gInit = (initWork + TB - 1) / TB;             // ~441

    // init: transposes, graph bounds, zero deg
    k_init<<<gInit, TB, 0, stream>>>(W1, W2, w1t, w2t, batch, gstart, n, G, deg);
    // degree count (scattered fire-and-forget atomics)
    k_deg<<<gE4, TB, 0, stream>>>(dstp, deg, E);
    // per-bucket headers: scan deg -> dinv, curpos, degree-sorted slot_hdr
    p2_hdr<<<nbuk, 128, 0, stream>>>(deg, dinv, curpos, slot_hdr, n);
    // place edges directly into CSR col
    k_place<<<gE4, TB, 0, stream>>>(srcp, dstp, curpos, colx, E);
    // layer 1 matmul -> fp8 scaled payload
    matmul_mfma<F_IN><<<gMM, TB, 0, stream>>>(x, w1t, dinv, xws8, n);
    // gather1 + fused matmul2 -> fp8 scaled layer-2 payload
    gather1_mm2<<<gS, TB, 0, stream>>>(slot_hdr, colx, (const uint2*)xws8,
                                       b1, w2t, xws8b, nslots, n);
    // gather2 -> bf16 h2 (pure, barrier-free)
    csr_gather8_fp8<<<gG8, TB, 0, stream>>>(slot_hdr, colx, (const uint2*)xws8b,
                                            b2, (bf16x8*)xh2, nslots, n);
    // pool + head
    pool_head<<<G, TB, 0, stream>>>(xh2, gstart, Wl, bl, out, G);
}

// Round 7
// 229.761 us; speedup vs baseline: 1.7129x; 1.7129x over previous
//
#include <hip/hip_runtime.h>
#include <hip/hip_bf16.h>
#include <cmath>

#define F_IN 128
#define HDIM 64
#define NPB 512          // nodes per bucket (node >> 9)
#define NB1 512          // edge chunks for the place kernel
#define CAP 9216         // col capacity per bucket (mean 8192, +11 sigma)

typedef __attribute__((ext_vector_type(8))) short bf16x8;
typedef __attribute__((ext_vector_type(4))) float f32x4;
typedef __attribute__((ext_vector_type(2))) float f32x2;

__device__ __forceinline__ float bf2f(unsigned short u) {
    union { unsigned int i; float f; } v; v.i = ((unsigned int)u) << 16; return v.f;
}
__device__ __forceinline__ unsigned short f2bf(float f) {
    __hip_bfloat16 h = __float2bfloat16(f);
    union { __hip_bfloat16 h; unsigned short u; } c; c.h = h; return c.u;
}
__device__ __forceinline__ unsigned char f2fp8(float f) {
    int p = __builtin_amdgcn_cvt_pk_fp8_f32(f, f, 0, false);
    return (unsigned char)(p & 0xff);
}
__device__ __forceinline__ void fp8x8_acc(uint2 v, float* a) {
    f32x2 f;
    f = __builtin_amdgcn_cvt_pk_f32_fp8(v.x, false); a[0] += f.x; a[1] += f.y;
    f = __builtin_amdgcn_cvt_pk_f32_fp8(v.x, true);  a[2] += f.x; a[3] += f.y;
    f = __builtin_amdgcn_cvt_pk_f32_fp8(v.y, false); a[4] += f.x; a[5] += f.y;
    f = __builtin_amdgcn_cvt_pk_f32_fp8(v.y, true);  a[6] += f.x; a[7] += f.y;
}
__device__ __forceinline__ void fp8x8_acc_m(uint2 v, float m, float* a) {
    f32x2 f;
    f = __builtin_amdgcn_cvt_pk_f32_fp8(v.x, false); a[0] = fmaf(f.x, m, a[0]); a[1] = fmaf(f.y, m, a[1]);
    f = __builtin_amdgcn_cvt_pk_f32_fp8(v.x, true);  a[2] = fmaf(f.x, m, a[2]); a[3] = fmaf(f.y, m, a[3]);
    f = __builtin_amdgcn_cvt_pk_f32_fp8(v.y, false); a[4] = fmaf(f.x, m, a[4]); a[5] = fmaf(f.y, m, a[5]);
    f = __builtin_amdgcn_cvt_pk_f32_fp8(v.y, true);  a[6] = fmaf(f.x, m, a[6]); a[7] = fmaf(f.y, m, a[7]);
}

// Gather: 8 lanes/slot, uint2 rows, 8-edge independent rounds; tail is ONE
// clamped+masked round (1 memory latency) instead of a serial dependent chain.
__device__ __forceinline__ void gather_rows(const int* __restrict__ col,
                                            const uint2* __restrict__ xws,
                                            int L, int s, int end, float* a) {
    int e = s;
    for (; e + 8 <= end; e += 8) {
        uint2 v0 = xws[(size_t)col[e + 0] * 8 + L];
        uint2 v1 = xws[(size_t)col[e + 1] * 8 + L];
        uint2 v2 = xws[(size_t)col[e + 2] * 8 + L];
        uint2 v3 = xws[(size_t)col[e + 3] * 8 + L];
        uint2 v4 = xws[(size_t)col[e + 4] * 8 + L];
        uint2 v5 = xws[(size_t)col[e + 5] * 8 + L];
        uint2 v6 = xws[(size_t)col[e + 6] * 8 + L];
        uint2 v7 = xws[(size_t)col[e + 7] * 8 + L];
        fp8x8_acc(v0, a); fp8x8_acc(v1, a); fp8x8_acc(v2, a); fp8x8_acc(v3, a);
        fp8x8_acc(v4, a); fp8x8_acc(v5, a); fp8x8_acc(v6, a); fp8x8_acc(v7, a);
    }
    if (e < end) {
        int last = end - 1;
        uint2 v0 = xws[(size_t)col[e]               * 8 + L];
        uint2 v1 = xws[(size_t)col[min(e + 1, last)] * 8 + L];
        uint2 v2 = xws[(size_t)col[min(e + 2, last)] * 8 + L];
        uint2 v3 = xws[(size_t)col[min(e + 3, last)] * 8 + L];
        uint2 v4 = xws[(size_t)col[min(e + 4, last)] * 8 + L];
        uint2 v5 = xws[(size_t)col[min(e + 5, last)] * 8 + L];
        uint2 v6 = xws[(size_t)col[min(e + 6, last)] * 8 + L];
        uint2 v7 = xws[(size_t)col[min(e + 7, last)] * 8 + L];
        fp8x8_acc(v0, a);
        fp8x8_acc_m(v1, (e + 1 < end) ? 1.0f : 0.0f, a);
        fp8x8_acc_m(v2, (e + 2 < end) ? 1.0f : 0.0f, a);
        fp8x8_acc_m(v3, (e + 3 < end) ? 1.0f : 0.0f, a);
        fp8x8_acc_m(v4, (e + 4 < end) ? 1.0f : 0.0f, a);
        fp8x8_acc_m(v5, (e + 5 < end) ? 1.0f : 0.0f, a);
        fp8x8_acc_m(v6, (e + 6 < end) ? 1.0f : 0.0f, a);
        fp8x8_acc_m(v7, (e + 7 < end) ? 1.0f : 0.0f, a);
    }
}

// ========== K1: init — W transposes + graph bounds + zero gcnt ==========

__launch_bounds__(256)
__global__ void k_init(const float* __restrict__ W1, const float* __restrict__ W2,
                       unsigned short* __restrict__ w1t, unsigned short* __restrict__ w2t,
                       const int* __restrict__ batch, int* __restrict__ gstart,
                       int n, int G, int* __restrict__ gcnt) {
    int t = blockIdx.x * 256 + threadIdx.x;
    if (t < F_IN * 64) {                       // w1t[c][k] = W1[k][c]
        int c = t & 63, k = t >> 6;
        w1t[c * F_IN + k] = f2bf(W1[t]);
        return;
    }
    t -= F_IN * 64;
    if (t < HDIM * 64) {                       // w2t[c][k] = W2[k][c]
        int c = t & 63, k = t >> 6;
        w2t[c * HDIM + k] = f2bf(W2[t]);
        return;
    }
    t -= HDIM * 64;
    if (t <= G) {                              // gstart: first node of graph t
        int g = t;
        int lo = 0, hi = n;
        while (lo < hi) {
            int mid = (lo + hi) >> 1;
            if (batch[mid] < g) lo = mid + 1; else hi = mid;
        }
        gstart[g] = lo;
        return;
    }
    t -= G + 1;
    if (t < 256) gcnt[t] = 0;
}

// ========== K2: fused histogram + place, 512-node buckets, 1024-thread blocks ==========
// Runs per (chunk,bucket) ~= 3125/196 = 16 edges = 64B -> minimal write amp.
// 1024 threads/block -> 32 waves/CU resident at grid 512.

__launch_bounds__(1024)
__global__ void p_place(const int* __restrict__ src, const int* __restrict__ dst,
                        int* __restrict__ gcnt, int* __restrict__ pairs,
                        int E, int nbuk, int chunk) {
    __shared__ int hist[256];
    __shared__ int cur[256];
    int tid = threadIdx.x;
    for (int i = tid; i < nbuk; i += 1024) hist[i] = 0;
    __syncthreads();
    int lo = blockIdx.x * chunk, hi = min(E, lo + chunk);
    for (int e = lo + tid; e < hi; e += 1024)
        atomicAdd(&hist[dst[e] >> 9], 1);
    __syncthreads();
    for (int i = tid; i < nbuk; i += 1024) {
        int c = hist[i];
        cur[i] = i * CAP + (c ? atomicAdd(&gcnt[i], c) : 0);
    }
    __syncthreads();
    for (int e = lo + tid; e < hi; e += 1024) {
        int d = dst[e];
        int pos = atomicAdd(&cur[d >> 9], 1);
        pairs[pos] = (src[e] << 9) | (d & 511);
    }
}

// ========== K3: per-bucket local CSR (512 nodes, LDS-staged) + degree-sorted headers ==========

__launch_bounds__(512)
__global__ void p2_csr(const int* __restrict__ pairs, const int* __restrict__ bucket_cnt,
                       float* __restrict__ dinv, int* __restrict__ col,
                       int4* __restrict__ slot_hdr, int n) {
    __shared__ int plds[CAP];
    __shared__ int dl[512];
    __shared__ int sc[512];
    __shared__ int cur[512];
    __shared__ int h64[64];
    __shared__ int s64[64];
    int b = blockIdx.x, tid = threadIdx.x;
    int nlo = b << 9;
    int eb = b * CAP;
    int cnt = bucket_cnt[b];
    dl[tid] = 0;
    if (tid < 64) h64[tid] = 0;
    __syncthreads();
    for (int i = tid; i < cnt; i += 512) {
        int v = pairs[eb + i];
        plds[i] = v;
        atomicAdd(&dl[v & 511], 1);
    }
    __syncthreads();
    int d0 = dl[tid];
    sc[tid] = d0;
    __syncthreads();
    for (int off = 1; off < 512; off <<= 1) {
        int a = (tid >= off) ? sc[tid - off] : 0;
        __syncthreads();
        sc[tid] += a;
        __syncthreads();
    }
    int excl = sc[tid] - d0;
    int node = nlo + tid;
    float dv = rsqrtf((float)(d0 + 1));
    if (node < n) dinv[node] = dv;
    cur[tid] = eb + excl;
    atomicAdd(&h64[min(d0, 63)], 1);
    __syncthreads();
    if (tid == 0) { int run = 0; for (int i = 0; i < 64; ++i) { s64[i] = run; run += h64[i]; } }
    __syncthreads();
    if (tid < 64) h64[tid] = 0;
    __syncthreads();
    {
        int bin = min(d0, 63);
        int pos = s64[bin] + atomicAdd(&h64[bin], 1);
        int4 hdr;
        hdr.x = (node < n) ? node : 0x7fffffff;
        hdr.y = eb + excl;
        hdr.z = d0;
        hdr.w = __float_as_int(dv);
        slot_hdr[nlo + pos] = hdr;
    }
    __syncthreads();
    for (int i = tid; i < cnt; i += 512) {
        unsigned int v = (unsigned int)plds[i];
        int pos = atomicAdd(&cur[v & 511], 1);
        col[pos] = (int)(v >> 9);
    }
}

// ========== K4: matmul1 (f32 X, K=128) -> fp8(xw * dinv) ==========

template <int K>
__launch_bounds__(256)
__global__ void matmul_mfma(const float* __restrict__ X, const unsigned short* __restrict__ Wt,
                            const float* __restrict__ dinv, unsigned char* __restrict__ out,
                            int n) {
    constexpr int KS  = K / 32;
    constexpr int LDX = K + 8;
    __shared__ unsigned short Xs[64 * LDX];
    __shared__ unsigned short Ws[64 * LDX];
    int tid = threadIdx.x;
    int rowbase = blockIdx.x * 64;
    for (int i = tid; i < 64 * (K / 8); i += 256) {
        int r = i / (K / 8), ch = i % (K / 8);
        *(bf16x8*)(Ws + r * LDX + ch * 8) = ((const bf16x8*)Wt)[i];
    }
    {
        const float4* X4 = (const float4*)X;
        for (int i = tid; i < 64 * (K / 4); i += 256) {
            int r = i / (K / 4), k4 = i % (K / 4);
            ushort4 u = { 0, 0, 0, 0 };
            int gr = rowbase + r;
            if (gr < n) {
                float4 v = X4[(size_t)gr * (K / 4) + k4];
                u.x = f2bf(v.x); u.y = f2bf(v.y); u.z = f2bf(v.z); u.w = f2bf(v.w);
            }
            *(ushort4*)(Xs + r * LDX + k4 * 4) = u;
        }
    }
    __syncthreads();
    int wave = tid >> 6, lane = tid & 63;
    int q = lane >> 4, nn = lane & 15;
    f32x4 acc[4] = {{0,0,0,0},{0,0,0,0},{0,0,0,0},{0,0,0,0}};
    int mrow = wave * 16 + nn;
#pragma unroll
    for (int s = 0; s < KS; ++s) {
        bf16x8 af = *(const bf16x8*)(Xs + mrow * LDX + s * 32 + q * 8);
#pragma unroll
        for (int c = 0; c < 4; ++c) {
            bf16x8 bf = *(const bf16x8*)(Ws + (c * 16 + nn) * LDX + s * 32 + q * 8);
            acc[c] = __builtin_amdgcn_mfma_f32_16x16x32_bf16(af, bf, acc[c], 0, 0, 0);
        }
    }
#pragma unroll
    for (int r = 0; r < 4; ++r) {
        int row = rowbase + wave * 16 + q * 4 + r;
        if (row >= n) continue;
        float dv = dinv[row];
#pragma unroll
        for (int c = 0; c < 4; ++c)
            out[(size_t)row * HDIM + c * 16 + nn] = f2fp8(acc[c][r] * dv);
    }
}

// ========== K5: gather1 + fused matmul2 (32-slot blocks) ==========

__launch_bounds__(256)
__global__ void gather1_mm2(const int4* __restrict__ slot_hdr, const int* __restrict__ col,
                            const uint2* __restrict__ xws, const float* __restrict__ bias,
                            const unsigned short* __restrict__ w2t,
                            unsigned char* __restrict__ out8, int nslots, int n) {
    __shared__ unsigned short Hs[32 * 72];   // h1 tile, bf16, row stride 72
    __shared__ unsigned short Ws[64 * 72];   // W2^T rows: Ws[c][k]
    __shared__ int   snode[32];
    __shared__ float sdinv[32];

    int tid = threadIdx.x;
    int ls = tid >> 3;          // local slot 0..31
    int L  = tid & 7;           // feature-octet lane
    int slot = blockIdx.x * 32 + ls;

    for (int i = tid; i < 64 * 8; i += 256) {
        int r = i >> 3, ch = i & 7;
        *(bf16x8*)(Ws + r * 72 + ch * 8) = ((const bf16x8*)w2t)[i];
    }

    // ---- gather phase ----
    int node = 0x7fffffff;
    float dv = 0.0f;
    float a[8] = {0, 0, 0, 0, 0, 0, 0, 0};
    if (slot < nslots) {
        int4 hdr = slot_hdr[slot];
        node = hdr.x;
        if (node < n) {
            dv = __int_as_float(hdr.w);
            fp8x8_acc(xws[(size_t)node * 8 + L], a);   // self-loop term
            gather_rows(col, xws, L, hdr.y, hdr.y + hdr.z, a);
        }
    }
    if (L == 0) { snode[ls] = node; sdinv[ls] = dv; }
    {
        int f0 = L * 8;
        bf16x8 o;
        if (node < n) {
#pragma unroll
            for (int j = 0; j < 8; ++j)
                o[j] = (short)f2bf(fmaxf(fmaf(a[j], dv, bias[f0 + j]), 0.0f));
        } else {
            short z[8] = {0,0,0,0,0,0,0,0};
            o = *(bf16x8*)z;
        }
        *(bf16x8*)(Hs + ls * 72 + L * 8) = o;
    }
    __syncthreads();

    // ---- matmul2 phase: D[32x64] = Hs @ W2, scaled by sdinv, emit fp8 ----
    int wave = tid >> 6, lane = tid & 63;
    int q = lane >> 4, nn = lane & 15;
    int mt  = wave & 1;          // M-tile (rows 0-15 / 16-31)
    int nt0 = (wave >> 1) * 2;   // N-tiles {nt0, nt0+1}
    f32x4 acc[2] = {{0,0,0,0},{0,0,0,0}};
#pragma unroll
    for (int s = 0; s < 2; ++s) {
        bf16x8 af = *(const bf16x8*)(Hs + (mt * 16 + nn) * 72 + s * 32 + q * 8);
#pragma unroll
        for (int t = 0; t < 2; ++t) {
            bf16x8 bf = *(const bf16x8*)(Ws + ((nt0 + t) * 16 + nn) * 72 + s * 32 + q * 8);
            acc[t] = __builtin_amdgcn_mfma_f32_16x16x32_bf16(af, bf, acc[t], 0, 0, 0);
        }
    }
#pragma unroll
    for (int r = 0; r < 4; ++r) {
        int lslot = mt * 16 + q * 4 + r;
        int nd = snode[lslot];
        if (nd >= n) continue;
        float dvr = sdinv[lslot];
#pragma unroll
        for (int t = 0; t < 2; ++t)
            out8[(size_t)nd * HDIM + (nt0 + t) * 16 + nn] = f2fp8(acc[t][r] * dvr);
    }
}

// ========== K6: gather2 — pure, barrier-free -> bf16 h2 ==========

__launch_bounds__(256)
__global__ void csr_gather8_fp8(const int4* __restrict__ slot_hdr, const int* __restrict__ col,
                                const uint2* __restrict__ xws, const float* __restrict__ bias,
                                bf16x8* __restrict__ outb, int nslots, int n) {
    int t = blockIdx.x * 256 + threadIdx.x;
    int slot = t >> 3;
    if (slot >= nslots) return;
    int L = t & 7;
    int4 hdr = slot_hdr[slot];
    int node = hdr.x;
    if (node >= n) return;
    float dv = __int_as_float(hdr.w);

    float a[8] = {0, 0, 0, 0, 0, 0, 0, 0};
    fp8x8_acc(xws[(size_t)node * 8 + L], a);
    gather_rows(col, xws, L, hdr.y, hdr.y + hdr.z, a);

    int f0 = L * 8;
    bf16x8 o;
#pragma unroll
    for (int j = 0; j < 8; ++j)
        o[j] = (short)f2bf(fmaxf(fmaf(a[j], dv, bias[f0 + j]), 0.0f));
    outb[(size_t)node * 8 + L] = o;
}

// ========== K7: mean-pool (bf16 rows) + head + sigmoid ==========

__launch_bounds__(256)
__global__ void pool_head(const unsigned short* __restrict__ h, const int* __restrict__ gstart,
                          const float* __restrict__ Wl, const float* __restrict__ bl,
                          float* __restrict__ out, int G) {
    int g = blockIdx.x;
    int s = gstart[g], e = gstart[g + 1];
    int f  = threadIdx.x & 63;
    int rg = threadIdx.x >> 6;
    float acc = 0.0f;
    for (int i = s + rg; i < e; i += 4)
        acc += bf2f(h[(size_t)i * HDIM + f]);
    __shared__ float red[4][HDIM];
    red[rg][f] = acc;
    __syncthreads();
    if (rg == 0) {
        float v = (red[0][f] + red[1][f]) + (red[2][f] + red[3][f]);
        float c = fmaxf((float)(e - s), 1.0f);
        v = v * Wl[f] * (1.0f / c);
#pragma unroll
        for (int off = 32; off; off >>= 1) v += __shfl_down(v, off, 64);
        if (f == 0) out[g] = 1.0f / (1.0f + expf(-(v + bl[0])));
    }
}

// ---------------- launch ----------------

extern "C" void kernel_launch(void* const* d_in, const int* in_sizes, int n_in,
                              void* d_out, int out_size, void* d_ws, size_t ws_size,
                              hipStream_t stream) {
    const float* x   = (const float*)d_in[0];
    const int* ei    = (const int*)d_in[1];
    const int* batch = (const int*)d_in[2];
    const float* W1  = (const float*)d_in[3];
    const float* b1  = (const float*)d_in[4];
    const float* W2  = (const float*)d_in[5];
    const float* b2  = (const float*)d_in[6];
    const float* Wl  = (const float*)d_in[7];
    const float* bl  = (const float*)d_in[8];
    float* out = (float*)d_out;

    const int n = in_sizes[0] / F_IN;   // 100000
    const int E = in_sizes[1] / 2;      // 1600000
    const int G = out_size;             // 512

    const int* srcp = ei;
    const int* dstp = ei + E;

    int nbuk = (n + NPB - 1) / NPB;     // 196
    int nslots = nbuk * NPB;            // 100352

    // workspace layout
    char* wsb = (char*)d_ws;
    auto alloc = [&](size_t bytes) { char* p = wsb; wsb += (bytes + 255) & ~(size_t)255; return p; };
    float* dinv       = (float*)alloc((size_t)n * 4);
    int4*  slot_hdr   = (int4*)alloc((size_t)nslots * 16);
    int*   gcnt       = (int*)alloc(256 * 4);
    int*   pairs      = (int*)alloc((size_t)nbuk * CAP * 4);
    int*   colx       = (int*)alloc((size_t)nbuk * CAP * 4);
    unsigned short* w1t  = (unsigned short*)alloc((size_t)F_IN * HDIM * 2);
    unsigned short* w2t  = (unsigned short*)alloc((size_t)HDIM * HDIM * 2);
    unsigned char*  xws8 = (unsigned char*)alloc((size_t)n * HDIM);       // fp8 payload L1
    unsigned char*  xws8b= (unsigned char*)alloc((size_t)n * HDIM);       // fp8 payload L2
    unsigned short* xh2  = (unsigned short*)alloc((size_t)n * HDIM * 2);  // layer-2 h (bf16)
    int*   gstart     = (int*)alloc(((size_t)G + 1) * 4);

    const int TB = 256;
    int gMM  = (n + 63) / 64;                         // 1563
    int chunk = (E + NB1 - 1) / NB1;                  // 3125
    int gG8  = (nslots * 8 + TB - 1) / TB;            // 3136
    int gS   = (nslots + 31) / 32;                    // 3136
    int initWork = F_IN * 64 + HDIM * 64 + (G + 1) + 256;
    int gInit = (initWork + TB - 1) / TB;

    // init: transposes, graph bounds, zero gcnt
    k_init<<<gInit, TB, 0, stream>>>(W1, W2, w1t, w2t, batch, gstart, n, G, gcnt);
    // fused histogram + place: 512-node buckets, 1024-thread blocks
    p_place<<<NB1, 1024, 0, stream>>>(srcp, dstp, gcnt, pairs, E, nbuk, chunk);
    // per-bucket CSR (512 nodes/bucket, pairs staged through LDS)
    p2_csr<<<nbuk, 512, 0, stream>>>(pairs, gcnt, dinv, colx, slot_hdr, n);
    // layer 1 matmul -> fp8 scaled payload
    matmul_mfma<F_IN><<<gMM, TB, 0, stream>>>(x, w1t, dinv, xws8, n);
    // gather1 + fused matmul2 -> fp8 scaled layer-2 payload
    gather1_mm2<<<gS, TB, 0, stream>>>(slot_hdr, colx, (const uint2*)xws8,
                                       b1, w2t, xws8b, nslots, n);
    // gather2 -> bf16 h2 (pure, barrier-free)
    csr_gather8_fp8<<<gG8, TB, 0, stream>>>(slot_hdr, colx, (const uint2*)xws8b,
                                            b2, (bf16x8*)xh2, nslots, n);
    // pool + head
    pool_head<<<G, TB, 0, stream>>>(xh2, gstart, Wl, bl, out, G);
}